// Round 20
// baseline (486.732 us; speedup 1.0000x reference)
//
#include <hip/hip_runtime.h>
#include <hip/hip_bf16.h>

#define NE 1600000
#define NN 100000
#define PSCALE 131072.0f   // 2^17 fixed-point scale for pooled accumulation

typedef __attribute__((ext_vector_type(8))) short s16x8;
typedef __attribute__((ext_vector_type(4))) float f32x4;
typedef __attribute__((ext_vector_type(16))) float f32x16;
typedef __attribute__((ext_vector_type(4))) int i32x4;
typedef __attribute__((ext_vector_type(4))) uint u32x4;

__device__ __forceinline__ ushort f2b(float v) {
  union { __hip_bfloat16 h; ushort u; } c; c.h = __float2bfloat16(v); return c.u;
}
// HW packed f32x2 -> bf16x2 (RNE). lo = a, hi = b. Verified on-device (r4-r19).
__device__ __forceinline__ uint cvtpk(float a, float b) {
  uint r;
  asm("v_cvt_pk_bf16_f32 %0, %1, %2" : "=v"(r) : "v"(a), "v"(b));
  return r;
}
__device__ __forceinline__ uint pkrelu(float a, float b) {
  a = fmaxf(a, 0.f); b = fmaxf(b, 0.f);
  return cvtpk(a, b);
}
__device__ __forceinline__ f32x16 mfma32(s16x8 a, s16x8 b, f32x16 c) {
  return __builtin_amdgcn_mfma_f32_32x32x16_bf16(a, b, c, 0, 0, 0);
}
// relu + pack reg-group g (regs 8g..8g+7) of a 32x32 C/D frag -> B-frag word
__device__ __forceinline__ u32x4 packg(const f32x16& a, int g) {
  u32x4 r;
#pragma unroll
  for (int w = 0; w < 4; w++) r[w] = pkrelu(a[8 * g + 2 * w], a[8 * g + 2 * w + 1]);
  return r;
}
// bias C-frag for output tile mt: reg r holds row (r&3)+8*(r>>2)+4*hi
__device__ __forceinline__ f32x16 loadbias(const float* bias, int mt, int hi) {
  f32x16 b;
#pragma unroll
  for (int q4 = 0; q4 < 4; q4++) {
    f32x4 v = *(const f32x4*)(bias + mt * 32 + q4 * 8 + hi * 4);
#pragma unroll
    for (int i = 0; i < 4; i++) b[q4 * 4 + i] = v[i];
  }
  return b;
}

// ---- prep: identical to r13-r19 (verified). Weights -> 32x32x16 A-frag order.
__global__ void prep_weights(const float* s0, const float* s1, const float* s2, const float* s3,
                             const float* s4, const float* s5, const float* s6, const float* s7,
                             const float* bm0, const float* bu0, ushort* dst) {
  const int NFRAG[8] = {4, 32, 32, 8, 4, 32, 32, 8};
  const int offs[8]  = {0, 2048, 18432, 34816, 38912, 40960, 57344, 73728};
  const float* srcs[8] = {s0, s1, s2, s3, s4, s5, s6, s7};
  int b = blockIdx.x;
  int cnt = NFRAG[b] * 512;
  const float* src = srcs[b];
  bool isProducer = (b == 0 || b == 4);
  bool isHead = (b == 3 || b == 7);
  int F1 = (b < 4) ? 5 : 2;
  int kbias = (b < 4) ? 13 : 10;
  const float* bp = (b < 4) ? bm0 : bu0;
  ushort* d = dst + offs[b];
  for (int idx = threadIdx.x; idx < cnt; idx += blockDim.x) {
    int f = idx >> 9, r = idx & 511, lane = r >> 3, j = r & 7;
    int hi = lane >> 5, m = lane & 31;
    float v = 0.f;
    if (isProducer) {
      int ch = f * 32 + m;
      int k = hi * 8 + j;
      int row = -1;
      if (k < 5) row = k;
      else if (k >= 8 && k < 8 + F1) row = k - 3;
      if (row >= 0) v = src[row * 128 + ch];
      else if (k == kbias) v = bp[ch];
    } else {
      int s = isHead ? f : (f >> 2);
      int k = s * 16 + hi * 8 + j;
      int c = (k & ~12) | ((k & 4) << 1) | ((k & 8) >> 1);   // swap bits 2,3
      if (isHead) v = (m < 2) ? src[c * 2 + m] : 0.f;
      else {
        int ch = (f & 3) * 32 + m;
        v = src[c * 128 + ch];
      }
    }
    d[idx] = f2b(v);
  }
}

// ---- main: r16 dataflow (verified), block = 1024 threads = 16 waves = 4 waves/SIMD
// with ONE block/CU (launch_bounds 2nd arg is CUDA-style min-blocks/CU — r4/r5/r19
// VGPR evidence). LDS 79KB single allocation; VGPR cap 128 (r16 needs 120).
template <int MODE>
__global__ __launch_bounds__(1024, 1)
void gnn_kernel(const float* __restrict__ nodes,
                const int* __restrict__ eidx,
                unsigned long long* __restrict__ pooled,
                const ushort* __restrict__ wsrc,
                const float* __restrict__ b1g, const float* __restrict__ b2g,
                const float* __restrict__ b3g,
                float* __restrict__ out) {
  __shared__ __align__(16) ushort wlds[38912];   // 76 frags x 1KB
  __shared__ __align__(16) float bias1[128];
  __shared__ __align__(16) float bias2[128];
  __shared__ __align__(16) float bias3[16];
  {
    i32x4* dw = (i32x4*)wlds;
    const i32x4* sw = (const i32x4*)wsrc;
    for (int i = threadIdx.x; i < 4864; i += 1024) dw[i] = sw[i];
    if (threadIdx.x < 128) {
      bias1[threadIdx.x] = b1g[threadIdx.x];
      bias2[threadIdx.x] = b2g[threadIdx.x];
    }
    if (threadIdx.x < 16) bias3[threadIdx.x] = (threadIdx.x < 2) ? b3g[threadIdx.x] : 0.f;
  }
  __syncthreads();

  const int wv = threadIdx.x >> 6;     // 0..15
  const int l = threadIdx.x & 63;
  const int hi = l >> 5;
  const int e32 = l & 31;
  auto LF = [&](int base, int f) {
    return *(const s16x8*)(wlds + base + f * 512 + l * 8);
  };

  int wid = blockIdx.x * 16 + wv;
  int nwv = gridDim.x * 16;
  const int NB = (MODE == 0) ? (NE / 64) : ((NN + 63) / 64);
  const f32x16 z16 = {0.f, 0.f, 0.f, 0.f, 0.f, 0.f, 0.f, 0.f,
                      0.f, 0.f, 0.f, 0.f, 0.f, 0.f, 0.f, 0.f};

  // gather: lane (e32, hi) loads endpoint hi of edges eg*32+e32, eg=0,1
  float g[2][5] = {{0.f, 0.f, 0.f, 0.f, 0.f}, {0.f, 0.f, 0.f, 0.f, 0.f}};
  auto PREF = [&](int bb) {
    if (bb < NB) {
#pragma unroll
      for (int eg = 0; eg < 2; eg++) {
        int e = (bb << 6) + (eg << 5) + e32;
        if (MODE == 0) {
          int idx = eidx[hi * NE + e];
          const float* np_ = nodes + idx * 5;
          g[eg][0] = np_[0]; g[eg][1] = np_[1]; g[eg][2] = np_[2];
          g[eg][3] = np_[3]; g[eg][4] = np_[4];
        } else if (e < NN) {
          if (hi == 0) {
            const float* np_ = nodes + e * 5;
            g[eg][0] = np_[0]; g[eg][1] = np_[1]; g[eg][2] = np_[2];
            g[eg][3] = np_[3]; g[eg][4] = np_[4];
          } else {
            unsigned long long pl = pooled[e];
            int x32 = (int)(uint)pl;
            int y32 = (int)(pl >> 32) + (x32 < 0 ? 1 : 0);
            g[eg][0] = (float)x32 * (1.f / PSCALE);
            g[eg][1] = (float)y32 * (1.f / PSCALE);
          }
        }
      }
    }
  };
  PREF(wid);

#pragma unroll 1
  for (int b = wid; b < NB; b += nwv) {
    const int rbase = b << 6;
    int rc0 = 0, rc1 = 0;
    if (MODE == 0 && hi == 0) {
      rc0 = eidx[NE + rbase + e32];
      rc1 = eidx[NE + rbase + 32 + e32];
    }
    // build L0 B-fragments (one per edge group)
    s16x8 xf[2];
#pragma unroll
    for (int eg = 0; eg < 2; eg++) {
      u32x4 f = {0u, 0u, 0u, 0u};
      if (MODE == 0) {
        f[0] = cvtpk(g[eg][0], g[eg][1]); f[1] = cvtpk(g[eg][2], g[eg][3]);
        f[2] = cvtpk(g[eg][4], hi ? 1.0f : 0.0f);      // bias rides k13 (hi=1,j=5)
      } else {
        if (hi == 0) {
          f[0] = cvtpk(g[eg][0], g[eg][1]); f[1] = cvtpk(g[eg][2], g[eg][3]);
          f[2] = cvtpk(g[eg][4], 0.f);
        } else {
          f[0] = cvtpk(g[eg][0], g[eg][1]); f[1] = cvtpk(1.0f, 0.f);  // bias k10
        }
      }
      xf[eg] = __builtin_bit_cast(s16x8, f);
    }
    PREF(b + nwv);

    // L0: 8 MFMA (bias folded into W0)
    u32x4 phA[4][2][2];   // [mt][group][eg] — all indices compile-time
    {
      s16x8 w0[4];
#pragma unroll
      for (int mt = 0; mt < 4; mt++) w0[mt] = LF(0, mt);
#pragma unroll
      for (int mt = 0; mt < 4; mt++) {
        f32x16 a0 = mfma32(w0[mt], xf[0], z16);
        f32x16 a1 = mfma32(w0[mt], xf[1], z16);
        phA[mt][0][0] = packg(a0, 0); phA[mt][1][0] = packg(a0, 1);
        phA[mt][0][1] = packg(a1, 0); phA[mt][1][1] = packg(a1, 1);
      }
    }
    // L1: per output tile, 8 frag reads feed 16 MFMAs (2 edge groups)
    u32x4 phB[4][2][2];
#pragma unroll
    for (int mt = 0; mt < 4; mt++) {
      s16x8 wf[8];
#pragma unroll
      for (int s = 0; s < 8; s++) wf[s] = LF(2048, s * 4 + mt);
      f32x16 a0 = loadbias(bias1, mt, hi);
      f32x16 a1 = a0;
#pragma unroll
      for (int s = 0; s < 8; s++) {
        a0 = mfma32(wf[s], __builtin_bit_cast(s16x8, phA[s >> 1][s & 1][0]), a0);
        a1 = mfma32(wf[s], __builtin_bit_cast(s16x8, phA[s >> 1][s & 1][1]), a1);
      }
      phB[mt][0][0] = packg(a0, 0); phB[mt][1][0] = packg(a0, 1);
      phB[mt][0][1] = packg(a1, 0); phB[mt][1][1] = packg(a1, 1);
    }
    // L2: same pattern
    u32x4 phC[4][2][2];
#pragma unroll
    for (int mt = 0; mt < 4; mt++) {
      s16x8 wf[8];
#pragma unroll
      for (int s = 0; s < 8; s++) wf[s] = LF(18432, s * 4 + mt);
      f32x16 a0 = loadbias(bias2, mt, hi);
      f32x16 a1 = a0;
#pragma unroll
      for (int s = 0; s < 8; s++) {
        a0 = mfma32(wf[s], __builtin_bit_cast(s16x8, phB[s >> 1][s & 1][0]), a0);
        a1 = mfma32(wf[s], __builtin_bit_cast(s16x8, phB[s >> 1][s & 1][1]), a1);
      }
      phC[mt][0][0] = packg(a0, 0); phC[mt][1][0] = packg(a0, 1);
      phC[mt][0][1] = packg(a1, 0); phC[mt][1][1] = packg(a1, 1);
    }
    // head: 16 MFMA (8 per edge group)
    f32x16 ah0, ah1;
    {
      s16x8 w3[8];
#pragma unroll
      for (int s = 0; s < 8; s++) w3[s] = LF(34816, s);
      ah0 = mfma32(w3[0], __builtin_bit_cast(s16x8, phC[0][0][0]), z16);
      ah1 = mfma32(w3[0], __builtin_bit_cast(s16x8, phC[0][0][1]), z16);
#pragma unroll
      for (int s = 1; s < 8; s++) {
        ah0 = mfma32(w3[s], __builtin_bit_cast(s16x8, phC[s >> 1][s & 1][0]), ah0);
        ah1 = mfma32(w3[s], __builtin_bit_cast(s16x8, phC[s >> 1][s & 1][1]), ah1);
      }
    }
    // epilogue
#pragma unroll
    for (int eg = 0; eg < 2; eg++) {
      int e = rbase + (eg << 5) + e32;
      const f32x16& a = eg ? ah1 : ah0;
      if (hi == 0) {
        float mv0 = a[0] + bias3[0], mv1 = a[1] + bias3[1];
        if (MODE == 0) {
          int ix = (int)rintf(mv0 * PSCALE);
          int iy = (int)rintf(mv1 * PSCALE);
          long long ad = (((long long)iy) << 32) + (long long)ix;
          atomicAdd(&pooled[eg ? rc1 : rc0], (unsigned long long)ad);
        } else if (e < NN) {
          out[e * 5 + 2] = nodes[e * 5 + 2] + mv0;
          out[e * 5 + 3] = nodes[e * 5 + 3] + mv1;
        }
      } else if (MODE == 1 && e < NN) {
        out[e * 5 + 0] = nodes[e * 5 + 0];
        out[e * 5 + 1] = nodes[e * 5 + 1];
        out[e * 5 + 4] = nodes[e * 5 + 4];
      }
    }
  }
}

extern "C" void kernel_launch(void* const* d_in, const int* in_sizes, int n_in,
                              void* d_out, int out_size, void* d_ws, size_t ws_size,
                              hipStream_t stream) {
  const float* nodes = (const float*)d_in[0];
  const int* eidx = (const int*)d_in[1];
  const float* Wm0 = (const float*)d_in[2];  const float* bm0 = (const float*)d_in[3];
  const float* Wm1 = (const float*)d_in[4];  const float* bm1 = (const float*)d_in[5];
  const float* Wm2 = (const float*)d_in[6];  const float* bm2 = (const float*)d_in[7];
  const float* Wm3 = (const float*)d_in[8];  const float* bm3 = (const float*)d_in[9];
  const float* Wu0 = (const float*)d_in[10]; const float* bu0 = (const float*)d_in[11];
  const float* Wu1 = (const float*)d_in[12]; const float* bu1 = (const float*)d_in[13];
  const float* Wu2 = (const float*)d_in[14]; const float* bu2 = (const float*)d_in[15];
  const float* Wu3 = (const float*)d_in[16]; const float* bu3 = (const float*)d_in[17];

  unsigned long long* pooled = (unsigned long long*)d_ws;  // NN u64 = 800000 B
  ushort* wbuf = (ushort*)((char*)d_ws + 800000);          // prearranged bf16 frags

  hipMemsetAsync(pooled, 0, NN * 8, stream);
  prep_weights<<<8, 256, 0, stream>>>(Wm0, Wm1, Wm2, Wm3, Wu0, Wu1, Wu2, Wu3,
                                      bm0, bu0, wbuf);

  // 1024 threads = 16 waves = 4 waves/SIMD, 1 block/CU (LDS 79360 B, VGPR<=128)
  gnn_kernel<0><<<256, 1024, 0, stream>>>(nodes, eidx, pooled, wbuf,
                                          bm1, bm2, bm3, nullptr);
  gnn_kernel<1><<<256, 1024, 0, stream>>>(nodes, nullptr, pooled, wbuf + 38912,
                                          bu1, bu2, bu3, (float*)d_out);
}

// Round 21
// 170.846 us; speedup vs baseline: 2.8490x; 2.8490x over previous
//
#include <hip/hip_runtime.h>
#include <hip/hip_bf16.h>

#define NE 1600000
#define NN 100000
#define PSCALE 131072.0f   // 2^17 fixed-point scale for pooled accumulation

typedef __attribute__((ext_vector_type(8))) short s16x8;
typedef __attribute__((ext_vector_type(4))) float f32x4;
typedef __attribute__((ext_vector_type(16))) float f32x16;
typedef __attribute__((ext_vector_type(4))) int i32x4;
typedef __attribute__((ext_vector_type(4))) uint u32x4;

__device__ __forceinline__ ushort f2b(float v) {
  union { __hip_bfloat16 h; ushort u; } c; c.h = __float2bfloat16(v); return c.u;
}
// HW packed f32x2 -> bf16x2 (RNE). lo = a, hi = b. Verified on-device (r4-r20).
__device__ __forceinline__ uint cvtpk(float a, float b) {
  uint r;
  asm("v_cvt_pk_bf16_f32 %0, %1, %2" : "=v"(r) : "v"(a), "v"(b));
  return r;
}
__device__ __forceinline__ uint pkrelu(float a, float b) {
  a = fmaxf(a, 0.f); b = fmaxf(b, 0.f);
  return cvtpk(a, b);
}
__device__ __forceinline__ f32x16 mfma32(s16x8 a, s16x8 b, f32x16 c) {
  return __builtin_amdgcn_mfma_f32_32x32x16_bf16(a, b, c, 0, 0, 0);
}
// relu + pack reg-group g (regs 8g..8g+7) of a 32x32 C/D frag -> B-frag word
__device__ __forceinline__ u32x4 packg(const f32x16& a, int g) {
  u32x4 r;
#pragma unroll
  for (int w = 0; w < 4; w++) r[w] = pkrelu(a[8 * g + 2 * w], a[8 * g + 2 * w + 1]);
  return r;
}
// bias C-frag for output tile mt: reg r holds row (r&3)+8*(r>>2)+4*hi
__device__ __forceinline__ f32x16 loadbias(const float* bias, int mt, int hi) {
  f32x16 b;
#pragma unroll
  for (int q4 = 0; q4 < 4; q4++) {
    f32x4 v = *(const f32x4*)(bias + mt * 32 + q4 * 8 + hi * 4);
#pragma unroll
    for (int i = 0; i < 4; i++) b[q4 * 4 + i] = v[i];
  }
  return b;
}

// ---- prep: identical to r13-r20 (verified). Weights -> 32x32x16 A-frag order.
__global__ void prep_weights(const float* s0, const float* s1, const float* s2, const float* s3,
                             const float* s4, const float* s5, const float* s6, const float* s7,
                             const float* bm0, const float* bu0, ushort* dst) {
  const int NFRAG[8] = {4, 32, 32, 8, 4, 32, 32, 8};
  const int offs[8]  = {0, 2048, 18432, 34816, 38912, 40960, 57344, 73728};
  const float* srcs[8] = {s0, s1, s2, s3, s4, s5, s6, s7};
  int b = blockIdx.x;
  int cnt = NFRAG[b] * 512;
  const float* src = srcs[b];
  bool isProducer = (b == 0 || b == 4);
  bool isHead = (b == 3 || b == 7);
  int F1 = (b < 4) ? 5 : 2;
  int kbias = (b < 4) ? 13 : 10;
  const float* bp = (b < 4) ? bm0 : bu0;
  ushort* d = dst + offs[b];
  for (int idx = threadIdx.x; idx < cnt; idx += blockDim.x) {
    int f = idx >> 9, r = idx & 511, lane = r >> 3, j = r & 7;
    int hi = lane >> 5, m = lane & 31;
    float v = 0.f;
    if (isProducer) {
      int ch = f * 32 + m;
      int k = hi * 8 + j;
      int row = -1;
      if (k < 5) row = k;
      else if (k >= 8 && k < 8 + F1) row = k - 3;
      if (row >= 0) v = src[row * 128 + ch];
      else if (k == kbias) v = bp[ch];
    } else {
      int s = isHead ? f : (f >> 2);
      int k = s * 16 + hi * 8 + j;
      int c = (k & ~12) | ((k & 4) << 1) | ((k & 8) >> 1);   // swap bits 2,3
      if (isHead) v = (m < 2) ? src[c * 2 + m] : 0.f;
      else {
        int ch = (f & 3) * 32 + m;
        v = src[c * 128 + ch];
      }
    }
    d[idx] = f2b(v);
  }
}

// ---- main: r15 base (best: 131us MODE0) + cross-batch software pipeline:
// head(b) (8-MFMA serial chain) overlaps with xf-build + L0 of batch b+nwv
// (pure register work, W0 hoisted to persistent regs). 32 edges/wave-batch,
// weights streamed from LDS, 32x32x16 MFMA, u64 fixed-point atomic.
template <int MODE>
__global__ __launch_bounds__(512, 1)
void gnn_kernel(const float* __restrict__ nodes,
                const int* __restrict__ eidx,
                unsigned long long* __restrict__ pooled,
                const ushort* __restrict__ wsrc,
                const float* __restrict__ b1g, const float* __restrict__ b2g,
                const float* __restrict__ b3g,
                float* __restrict__ out) {
  __shared__ __align__(16) ushort wlds[38912];   // 76 frags x 1KB
  __shared__ __align__(16) float bias1[128];
  __shared__ __align__(16) float bias2[128];
  __shared__ __align__(16) float bias3[16];
  {
    i32x4* dw = (i32x4*)wlds;
    const i32x4* sw = (const i32x4*)wsrc;
    for (int i = threadIdx.x; i < 4864; i += 512) dw[i] = sw[i];
    if (threadIdx.x < 128) {
      bias1[threadIdx.x] = b1g[threadIdx.x];
      bias2[threadIdx.x] = b2g[threadIdx.x];
    }
    if (threadIdx.x < 16) bias3[threadIdx.x] = (threadIdx.x < 2) ? b3g[threadIdx.x] : 0.f;
  }
  __syncthreads();

  const int wv = threadIdx.x >> 6;
  const int l = threadIdx.x & 63;
  const int hi = l >> 5;
  const int e32 = l & 31;
  auto LF = [&](int base, int f) {
    return *(const s16x8*)(wlds + base + f * 512 + l * 8);
  };

  int wid = blockIdx.x * 8 + wv;
  int nwv = gridDim.x * 8;
  const int NB = (MODE == 0) ? (NE / 32) : (NN / 32);   // both divide exactly
  const f32x16 z16 = {0.f, 0.f, 0.f, 0.f, 0.f, 0.f, 0.f, 0.f,
                      0.f, 0.f, 0.f, 0.f, 0.f, 0.f, 0.f, 0.f};

  // W0 persistent in registers (16 VGPRs): L0 becomes pure-register work
  s16x8 w0p[4];
#pragma unroll
  for (int mt = 0; mt < 4; mt++) w0p[mt] = LF(0, mt);

  // gather regs: lane (e32,hi) loads endpoint hi of edge (bb<<5)+e32
  float g0 = 0, g1 = 0, g2 = 0, g3 = 0, g4 = 0;
  auto PREF = [&](int bb) {
    if (bb < NB) {
      int e = (bb << 5) + e32;
      if (MODE == 0) {
        int idx = eidx[hi * NE + e];
        const float* np_ = nodes + idx * 5;
        g0 = np_[0]; g1 = np_[1]; g2 = np_[2]; g3 = np_[3]; g4 = np_[4];
      } else {
        if (hi == 0) {
          const float* np_ = nodes + e * 5;
          g0 = np_[0]; g1 = np_[1]; g2 = np_[2]; g3 = np_[3]; g4 = np_[4];
        } else {
          unsigned long long pl = pooled[e];
          int x32 = (int)(uint)pl;
          int y32 = (int)(pl >> 32) + (x32 < 0 ? 1 : 0);
          g0 = (float)x32 * (1.f / PSCALE);
          g1 = (float)y32 * (1.f / PSCALE);
        }
      }
    }
  };
  s16x8 xf;
  auto BUILDXF = [&]() {
    u32x4 f = {0u, 0u, 0u, 0u};
    if (MODE == 0) {
      f[0] = cvtpk(g0, g1); f[1] = cvtpk(g2, g3);
      f[2] = cvtpk(g4, hi ? 1.0f : 0.0f);            // bias rides k13 (hi=1,j=5)
    } else {
      if (hi == 0) { f[0] = cvtpk(g0, g1); f[1] = cvtpk(g2, g3); f[2] = cvtpk(g4, 0.f); }
      else         { f[0] = cvtpk(g0, g1); f[1] = cvtpk(1.0f, 0.f); }  // bias k10
    }
    xf = __builtin_bit_cast(s16x8, f);
  };
  u32x4 phA[4][2];
  auto L0 = [&]() {
#pragma unroll
    for (int mt = 0; mt < 4; mt++) {
      f32x16 a = mfma32(w0p[mt], xf, z16);
      phA[mt][0] = packg(a, 0);
      phA[mt][1] = packg(a, 1);
    }
  };

  // prologue: phA for the first batch
  PREF(wid);
  if (wid < NB) {
    BUILDXF();
    PREF(wid + nwv);
    L0();
  }

#pragma unroll 1
  for (int b = wid; b < NB; b += nwv) {
    const int rbase = b << 5;
    int rc = 0;
    if (MODE == 0) rc = eidx[NE + rbase + e32];
    // L1: phA -> phB (weights streamed from LDS)
    u32x4 phB[4][2];
#pragma unroll
    for (int mt = 0; mt < 4; mt++) {
      s16x8 wf[8];
#pragma unroll
      for (int s = 0; s < 8; s++) wf[s] = LF(2048, s * 4 + mt);
      f32x16 a = loadbias(bias1, mt, hi);
#pragma unroll
      for (int s = 0; s < 8; s++)
        a = mfma32(wf[s], __builtin_bit_cast(s16x8, phA[s >> 1][s & 1]), a);
      phB[mt][0] = packg(a, 0);
      phB[mt][1] = packg(a, 1);
    }
    // L2: phB -> phC
    u32x4 phC[4][2];
#pragma unroll
    for (int mt = 0; mt < 4; mt++) {
      s16x8 wf[8];
#pragma unroll
      for (int s = 0; s < 8; s++) wf[s] = LF(18432, s * 4 + mt);
      f32x16 a = loadbias(bias2, mt, hi);
#pragma unroll
      for (int s = 0; s < 8; s++)
        a = mfma32(wf[s], __builtin_bit_cast(s16x8, phB[s >> 1][s & 1]), a);
      phC[mt][0] = packg(a, 0);
      phC[mt][1] = packg(a, 1);
    }
    // issue W3 loads early; their latency hides under next-batch L0
    s16x8 w3[8];
#pragma unroll
    for (int s = 0; s < 8; s++) w3[s] = LF(34816, s);
    // next-batch xf + L0 (pure register work, independent of head(b))
    int b2 = b + nwv;
    if (b2 < NB) {
      BUILDXF();
      PREF(b2 + nwv);
      L0();
    }
    // head(b): 8-MFMA serial chain on phC — overlaps with L0 above
    f32x16 ah = mfma32(w3[0], __builtin_bit_cast(s16x8, phC[0][0]), z16);
#pragma unroll
    for (int s = 1; s < 8; s++)
      ah = mfma32(w3[s], __builtin_bit_cast(s16x8, phC[s >> 1][s & 1]), ah);

    // epilogue
    int e = rbase + e32;
    if (hi == 0) {
      float mv0 = ah[0] + bias3[0], mv1 = ah[1] + bias3[1];
      if (MODE == 0) {
        int ix = (int)rintf(mv0 * PSCALE);
        int iy = (int)rintf(mv1 * PSCALE);
        long long ad = (((long long)iy) << 32) + (long long)ix;
        atomicAdd(&pooled[rc], (unsigned long long)ad);
      } else {
        out[e * 5 + 2] = nodes[e * 5 + 2] + mv0;
        out[e * 5 + 3] = nodes[e * 5 + 3] + mv1;
      }
    } else if (MODE == 1) {
      out[e * 5 + 0] = nodes[e * 5 + 0];
      out[e * 5 + 1] = nodes[e * 5 + 1];
      out[e * 5 + 4] = nodes[e * 5 + 4];
    }
  }
}

extern "C" void kernel_launch(void* const* d_in, const int* in_sizes, int n_in,
                              void* d_out, int out_size, void* d_ws, size_t ws_size,
                              hipStream_t stream) {
  const float* nodes = (const float*)d_in[0];
  const int* eidx = (const int*)d_in[1];
  const float* Wm0 = (const float*)d_in[2];  const float* bm0 = (const float*)d_in[3];
  const float* Wm1 = (const float*)d_in[4];  const float* bm1 = (const float*)d_in[5];
  const float* Wm2 = (const float*)d_in[6];  const float* bm2 = (const float*)d_in[7];
  const float* Wm3 = (const float*)d_in[8];  const float* bm3 = (const float*)d_in[9];
  const float* Wu0 = (const float*)d_in[10]; const float* bu0 = (const float*)d_in[11];
  const float* Wu1 = (const float*)d_in[12]; const float* bu1 = (const float*)d_in[13];
  const float* Wu2 = (const float*)d_in[14]; const float* bu2 = (const float*)d_in[15];
  const float* Wu3 = (const float*)d_in[16]; const float* bu3 = (const float*)d_in[17];

  unsigned long long* pooled = (unsigned long long*)d_ws;  // NN u64 = 800000 B
  ushort* wbuf = (ushort*)((char*)d_ws + 800000);          // prearranged bf16 frags

  hipMemsetAsync(pooled, 0, NN * 8, stream);
  prep_weights<<<8, 256, 0, stream>>>(Wm0, Wm1, Wm2, Wm3, Wu0, Wu1, Wu2, Wu3,
                                      bm0, bu0, wbuf);

  gnn_kernel<0><<<256, 512, 0, stream>>>(nodes, eidx, pooled, wbuf,
                                         bm1, bm2, bm3, nullptr);
  gnn_kernel<1><<<256, 512, 0, stream>>>(nodes, nullptr, pooled, wbuf + 38912,
                                         bu1, bu2, bu3, (float*)d_out);
}

// Round 22
// 166.943 us; speedup vs baseline: 2.9156x; 1.0234x over previous
//
#include <hip/hip_runtime.h>
#include <hip/hip_bf16.h>

#define NE 1600000
#define NN 100000
#define PSCALE 131072.0f   // 2^17 fixed-point scale for pooled accumulation

typedef __attribute__((ext_vector_type(8))) short s16x8;
typedef __attribute__((ext_vector_type(4))) float f32x4;
typedef __attribute__((ext_vector_type(16))) float f32x16;
typedef __attribute__((ext_vector_type(4))) int i32x4;
typedef __attribute__((ext_vector_type(4))) uint u32x4;

__device__ __forceinline__ ushort f2b(float v) {
  union { __hip_bfloat16 h; ushort u; } c; c.h = __float2bfloat16(v); return c.u;
}
// HW packed f32x2 -> bf16x2 (RNE). lo = a, hi = b. Verified on-device (r4-r21).
__device__ __forceinline__ uint cvtpk(float a, float b) {
  uint r;
  asm("v_cvt_pk_bf16_f32 %0, %1, %2" : "=v"(r) : "v"(a), "v"(b));
  return r;
}
__device__ __forceinline__ uint pkrelu(float a, float b) {
  a = fmaxf(a, 0.f); b = fmaxf(b, 0.f);
  return cvtpk(a, b);
}
__device__ __forceinline__ f32x16 mfma32(s16x8 a, s16x8 b, f32x16 c) {
  return __builtin_amdgcn_mfma_f32_32x32x16_bf16(a, b, c, 0, 0, 0);
}
// relu + pack reg-group g (regs 8g..8g+7) of a 32x32 C/D frag -> B-frag word
__device__ __forceinline__ u32x4 packg(const f32x16& a, int g) {
  u32x4 r;
#pragma unroll
  for (int w = 0; w < 4; w++) r[w] = pkrelu(a[8 * g + 2 * w], a[8 * g + 2 * w + 1]);
  return r;
}
// bias C-frag for output tile mt: reg r holds row (r&3)+8*(r>>2)+4*hi
__device__ __forceinline__ f32x16 loadbias(const float* bias, int mt, int hi) {
  f32x16 b;
#pragma unroll
  for (int q4 = 0; q4 < 4; q4++) {
    f32x4 v = *(const f32x4*)(bias + mt * 32 + q4 * 8 + hi * 4);
#pragma unroll
    for (int i = 0; i < 4; i++) b[q4 * 4 + i] = v[i];
  }
  return b;
}

// ---- prep: identical to r13-r21 (verified). Weights -> 32x32x16 A-frag order.
__global__ void prep_weights(const float* s0, const float* s1, const float* s2, const float* s3,
                             const float* s4, const float* s5, const float* s6, const float* s7,
                             const float* bm0, const float* bu0, ushort* dst) {
  const int NFRAG[8] = {4, 32, 32, 8, 4, 32, 32, 8};
  const int offs[8]  = {0, 2048, 18432, 34816, 38912, 40960, 57344, 73728};
  const float* srcs[8] = {s0, s1, s2, s3, s4, s5, s6, s7};
  int b = blockIdx.x;
  int cnt = NFRAG[b] * 512;
  const float* src = srcs[b];
  bool isProducer = (b == 0 || b == 4);
  bool isHead = (b == 3 || b == 7);
  int F1 = (b < 4) ? 5 : 2;
  int kbias = (b < 4) ? 13 : 10;
  const float* bp = (b < 4) ? bm0 : bu0;
  ushort* d = dst + offs[b];
  for (int idx = threadIdx.x; idx < cnt; idx += blockDim.x) {
    int f = idx >> 9, r = idx & 511, lane = r >> 3, j = r & 7;
    int hi = lane >> 5, m = lane & 31;
    float v = 0.f;
    if (isProducer) {
      int ch = f * 32 + m;
      int k = hi * 8 + j;
      int row = -1;
      if (k < 5) row = k;
      else if (k >= 8 && k < 8 + F1) row = k - 3;
      if (row >= 0) v = src[row * 128 + ch];
      else if (k == kbias) v = bp[ch];
    } else {
      int s = isHead ? f : (f >> 2);
      int k = s * 16 + hi * 8 + j;
      int c = (k & ~12) | ((k & 4) << 1) | ((k & 8) >> 1);   // swap bits 2,3
      if (isHead) v = (m < 2) ? src[c * 2 + m] : 0.f;
      else {
        int ch = (f & 3) * 32 + m;
        v = src[c * 128 + ch];
      }
    }
    d[idx] = f2b(v);
  }
}

// ---- main: r15 structure (best measured), LDS shrunk to W1+W2+W3 (73.7KB) so
// TWO blocks can co-reside per CU (grid 512) -> target 4 waves/SIMD. W0's 4
// fragments live in persistent registers (loaded once from global, L2-hot).
// 32 edges/wave-batch, 32x32x16 MFMA, u64 fixed-point atomic, no main-loop barriers.
template <int MODE>
__global__ __launch_bounds__(512, 2)
void gnn_kernel(const float* __restrict__ nodes,
                const int* __restrict__ eidx,
                unsigned long long* __restrict__ pooled,
                const ushort* __restrict__ wsrc,
                const float* __restrict__ b1g, const float* __restrict__ b2g,
                const float* __restrict__ b3g,
                float* __restrict__ out) {
  __shared__ __align__(16) ushort wlds[36864];   // W1(16384) W2(16384) W3(4096) ushorts
  __shared__ __align__(16) float bias1[128];
  __shared__ __align__(16) float bias2[128];
  __shared__ __align__(16) float bias3[16];
  {
    i32x4* dw = (i32x4*)wlds;
    const i32x4* sw = (const i32x4*)wsrc;
    for (int i = threadIdx.x; i < 4608; i += 512) dw[i] = sw[256 + i];  // skip W0
    if (threadIdx.x < 128) {
      bias1[threadIdx.x] = b1g[threadIdx.x];
      bias2[threadIdx.x] = b2g[threadIdx.x];
    }
    if (threadIdx.x < 16) bias3[threadIdx.x] = (threadIdx.x < 2) ? b3g[threadIdx.x] : 0.f;
  }

  const int wv = threadIdx.x >> 6;
  const int l = threadIdx.x & 63;
  const int hi = l >> 5;
  const int e32 = l & 31;
  // LDS frag fetch (bases in ushort units): W1=0, W2=16384, W3=32768
  auto LF = [&](int base, int f) {
    return *(const s16x8*)(wlds + base + f * 512 + l * 8);
  };
  // W0 persistent in registers (16 VGPRs), straight from global (L2-hot, once)
  s16x8 w0p[4];
#pragma unroll
  for (int mt = 0; mt < 4; mt++)
    w0p[mt] = *(const s16x8*)(wsrc + ((mt * 64 + l) * 8));
  __syncthreads();

  int wid = blockIdx.x * 8 + wv;
  int nwv = gridDim.x * 8;
  const int NB = (MODE == 0) ? (NE / 32) : (NN / 32);
  const f32x16 z16 = {0.f, 0.f, 0.f, 0.f, 0.f, 0.f, 0.f, 0.f,
                      0.f, 0.f, 0.f, 0.f, 0.f, 0.f, 0.f, 0.f};

  // gather: lane = (edge e32, half hi). hi0 = sender/node, hi1 = receiver/pooled.
  float g0 = 0, g1 = 0, g2 = 0, g3 = 0, g4 = 0;
  auto PREF = [&](int bb) {
    if (bb < NB) {
      int e = (bb << 5) + e32;
      if (MODE == 0) {
        int idx = eidx[hi * NE + e];
        const float* np_ = nodes + idx * 5;
        g0 = np_[0]; g1 = np_[1]; g2 = np_[2]; g3 = np_[3]; g4 = np_[4];
      } else {
        if (hi == 0) {
          const float* np_ = nodes + e * 5;
          g0 = np_[0]; g1 = np_[1]; g2 = np_[2]; g3 = np_[3]; g4 = np_[4];
        } else {
          unsigned long long pl = pooled[e];
          int x32 = (int)(uint)pl;
          int y32 = (int)(pl >> 32) + (x32 < 0 ? 1 : 0);
          g0 = (float)x32 * (1.f / PSCALE);
          g1 = (float)y32 * (1.f / PSCALE);
        }
      }
    }
  };
  PREF(wid);

#pragma unroll 1
  for (int b = wid; b < NB; b += nwv) {
    const int rbase = b << 5;
    int rc = 0;
    if (MODE == 0) rc = eidx[NE + rbase + e32];
    // build the single L0 B-fragment
    s16x8 xf;
    {
      u32x4 f = {0u, 0u, 0u, 0u};
      if (MODE == 0) {
        f[0] = cvtpk(g0, g1); f[1] = cvtpk(g2, g3);
        f[2] = cvtpk(g4, hi ? 1.0f : 0.0f);          // bias rides k13 (hi=1,j=5)
      } else {
        if (hi == 0) { f[0] = cvtpk(g0, g1); f[1] = cvtpk(g2, g3); f[2] = cvtpk(g4, 0.f); }
        else         { f[0] = cvtpk(g0, g1); f[1] = cvtpk(1.0f, 0.f); }  // bias k10
      }
      xf = __builtin_bit_cast(s16x8, f);
    }
    PREF(b + nwv);

    // prefetch L1 mt=0 (8 frags) before any MFMA
    s16x8 wf[2][8];
#pragma unroll
    for (int s = 0; s < 8; s++) wf[0][s] = LF(0, s * 4);

    // L0: 4 MFMA (bias folded into W0, W0 in registers)
    u32x4 phA[4][2];
    {
      f32x16 a;
      a = mfma32(w0p[0], xf, z16); phA[0][0] = packg(a, 0); phA[0][1] = packg(a, 1);
      a = mfma32(w0p[1], xf, z16); phA[1][0] = packg(a, 0); phA[1][1] = packg(a, 1);
      a = mfma32(w0p[2], xf, z16); phA[2][0] = packg(a, 0); phA[2][1] = packg(a, 1);
      a = mfma32(w0p[3], xf, z16); phA[3][0] = packg(a, 0); phA[3][1] = packg(a, 1);
    }
    // L1: stream 32 frags, double-buffered by output tile; mt=3 preloads L2 mt=0
    u32x4 phB[4][2];
#pragma unroll
    for (int mt = 0; mt < 4; mt++) {
      if (mt < 3) {
#pragma unroll
        for (int s = 0; s < 8; s++) wf[(mt + 1) & 1][s] = LF(0, s * 4 + mt + 1);
      } else {
#pragma unroll
        for (int s = 0; s < 8; s++) wf[(mt + 1) & 1][s] = LF(16384, s * 4);
      }
      f32x16 a = loadbias(bias1, mt, hi);
#pragma unroll
      for (int s = 0; s < 8; s++)
        a = mfma32(wf[mt & 1][s], __builtin_bit_cast(s16x8, phA[s >> 1][s & 1]), a);
      phB[mt][0] = packg(a, 0);
      phB[mt][1] = packg(a, 1);
    }
    // L2: same stream; mt=3 preloads W3
    u32x4 phC[4][2];
#pragma unroll
    for (int mt = 0; mt < 4; mt++) {
      if (mt < 3) {
#pragma unroll
        for (int s = 0; s < 8; s++) wf[(mt + 1) & 1][s] = LF(16384, s * 4 + mt + 1);
      } else {
#pragma unroll
        for (int s = 0; s < 8; s++) wf[(mt + 1) & 1][s] = LF(32768, s);
      }
      f32x16 a = loadbias(bias2, mt, hi);
#pragma unroll
      for (int s = 0; s < 8; s++)
        a = mfma32(wf[mt & 1][s], __builtin_bit_cast(s16x8, phB[s >> 1][s & 1]), a);
      phC[mt][0] = packg(a, 0);
      phC[mt][1] = packg(a, 1);
    }
    // head: 8 MFMA chain; W3 frags already in wf[0]
    f32x16 a = mfma32(wf[0][0], __builtin_bit_cast(s16x8, phC[0][0]), z16);
#pragma unroll
    for (int s = 1; s < 8; s++)
      a = mfma32(wf[0][s], __builtin_bit_cast(s16x8, phC[s >> 1][s & 1]), a);

    int e = rbase + e32;
    if (hi == 0) {
      float mv0 = a[0] + bias3[0], mv1 = a[1] + bias3[1];
      if (MODE == 0) {
        // ONE exact fixed-point u64 atomic per edge (r14, verified)
        int ix = (int)rintf(mv0 * PSCALE);
        int iy = (int)rintf(mv1 * PSCALE);
        long long ad = (((long long)iy) << 32) + (long long)ix;
        atomicAdd(&pooled[rc], (unsigned long long)ad);
      } else {
        out[e * 5 + 2] = nodes[e * 5 + 2] + mv0;
        out[e * 5 + 3] = nodes[e * 5 + 3] + mv1;
      }
    } else if (MODE == 1) {
      out[e * 5 + 0] = nodes[e * 5 + 0];
      out[e * 5 + 1] = nodes[e * 5 + 1];
      out[e * 5 + 4] = nodes[e * 5 + 4];
    }
  }
}

extern "C" void kernel_launch(void* const* d_in, const int* in_sizes, int n_in,
                              void* d_out, int out_size, void* d_ws, size_t ws_size,
                              hipStream_t stream) {
  const float* nodes = (const float*)d_in[0];
  const int* eidx = (const int*)d_in[1];
  const float* Wm0 = (const float*)d_in[2];  const float* bm0 = (const float*)d_in[3];
  const float* Wm1 = (const float*)d_in[4];  const float* bm1 = (const float*)d_in[5];
  const float* Wm2 = (const float*)d_in[6];  const float* bm2 = (const float*)d_in[7];
  const float* Wm3 = (const float*)d_in[8];  const float* bm3 = (const float*)d_in[9];
  const float* Wu0 = (const float*)d_in[10]; const float* bu0 = (const float*)d_in[11];
  const float* Wu1 = (const float*)d_in[12]; const float* bu1 = (const float*)d_in[13];
  const float* Wu2 = (const float*)d_in[14]; const float* bu2 = (const float*)d_in[15];
  const float* Wu3 = (const float*)d_in[16]; const float* bu3 = (const float*)d_in[17];

  unsigned long long* pooled = (unsigned long long*)d_ws;  // NN u64 = 800000 B
  ushort* wbuf = (ushort*)((char*)d_ws + 800000);          // prearranged bf16 frags

  hipMemsetAsync(pooled, 0, NN * 8, stream);
  prep_weights<<<8, 256, 0, stream>>>(Wm0, Wm1, Wm2, Wm3, Wu0, Wu1, Wu2, Wu3,
                                      bm0, bu0, wbuf);

  // 74.8KB LDS/block -> 2 blocks/CU possible; grid 512 = 2 blocks x 256 CU
  gnn_kernel<0><<<512, 512, 0, stream>>>(nodes, eidx, pooled, wbuf,
                                         bm1, bm2, bm3, nullptr);
  gnn_kernel<1><<<512, 512, 0, stream>>>(nodes, nullptr, pooled, wbuf + 38912,
                                         bu1, bu2, bu3, (float*)d_out);
}

// Round 23
// 156.414 us; speedup vs baseline: 3.1118x; 1.0673x over previous
//
#include <hip/hip_runtime.h>
#include <hip/hip_bf16.h>

#define NE 1600000
#define NN 100000
#define PSCALE 131072.0f   // 2^17 fixed-point scale for pooled accumulation

typedef __attribute__((ext_vector_type(8))) short s16x8;
typedef __attribute__((ext_vector_type(4))) float f32x4;
typedef __attribute__((ext_vector_type(16))) float f32x16;
typedef __attribute__((ext_vector_type(4))) int i32x4;
typedef __attribute__((ext_vector_type(4))) uint u32x4;

__device__ __forceinline__ ushort f2b(float v) {
  union { __hip_bfloat16 h; ushort u; } c; c.h = __float2bfloat16(v); return c.u;
}
// HW packed f32x2 -> bf16x2 (RNE). lo = a, hi = b. Verified on-device (r4-r22).
__device__ __forceinline__ uint cvtpk(float a, float b) {
  uint r;
  asm("v_cvt_pk_bf16_f32 %0, %1, %2" : "=v"(r) : "v"(a), "v"(b));
  return r;
}
__device__ __forceinline__ uint pkrelu(float a, float b) {
  a = fmaxf(a, 0.f); b = fmaxf(b, 0.f);
  return cvtpk(a, b);
}
__device__ __forceinline__ f32x16 mfma32(s16x8 a, s16x8 b, f32x16 c) {
  return __builtin_amdgcn_mfma_f32_32x32x16_bf16(a, b, c, 0, 0, 0);
}
// relu + pack reg-group g (regs 8g..8g+7) of a 32x32 C/D frag -> B-frag word
__device__ __forceinline__ u32x4 packg(const f32x16& a, int g) {
  u32x4 r;
#pragma unroll
  for (int w = 0; w < 4; w++) r[w] = pkrelu(a[8 * g + 2 * w], a[8 * g + 2 * w + 1]);
  return r;
}
// bias C-frag for output tile mt: reg r holds row (r&3)+8*(r>>2)+4*hi
__device__ __forceinline__ f32x16 loadbias(const float* bias, int mt, int hi) {
  f32x16 b;
#pragma unroll
  for (int q4 = 0; q4 < 4; q4++) {
    f32x4 v = *(const f32x4*)(bias + mt * 32 + q4 * 8 + hi * 4);
#pragma unroll
    for (int i = 0; i < 4; i++) b[q4 * 4 + i] = v[i];
  }
  return b;
}

// ---- prep: r13-r22 logic (verified), widened to 64 blocks (8 parts/table);
// blocks 64..79 zero the pooled accumulator (replaces the separate memset).
__global__ void prep_weights(const float* s0, const float* s1, const float* s2, const float* s3,
                             const float* s4, const float* s5, const float* s6, const float* s7,
                             const float* bm0, const float* bu0, ushort* dst,
                             unsigned long long* pooled) {
  if (blockIdx.x >= 64) {
    for (int i = (blockIdx.x - 64) * 256 + threadIdx.x; i < NN; i += 16 * 256)
      pooled[i] = 0ULL;
    return;
  }
  const int NFRAG[8] = {4, 32, 32, 8, 4, 32, 32, 8};
  const int offs[8]  = {0, 2048, 18432, 34816, 38912, 40960, 57344, 73728};
  int part = blockIdx.x & 7;
  int b = blockIdx.x >> 3;
  const float* srcs[8] = {s0, s1, s2, s3, s4, s5, s6, s7};
  int cnt = NFRAG[b] * 512;
  const float* src = srcs[b];
  bool isProducer = (b == 0 || b == 4);
  bool isHead = (b == 3 || b == 7);
  int F1 = (b < 4) ? 5 : 2;
  int kbias = (b < 4) ? 13 : 10;
  const float* bp = (b < 4) ? bm0 : bu0;
  ushort* d = dst + offs[b];
  for (int idx = part * 256 + threadIdx.x; idx < cnt; idx += 2048) {
    int f = idx >> 9, r = idx & 511, lane = r >> 3, j = r & 7;
    int hi = lane >> 5, m = lane & 31;
    float v = 0.f;
    if (isProducer) {
      int ch = f * 32 + m;
      int k = hi * 8 + j;
      int row = -1;
      if (k < 5) row = k;
      else if (k >= 8 && k < 8 + F1) row = k - 3;
      if (row >= 0) v = src[row * 128 + ch];
      else if (k == kbias) v = bp[ch];
    } else {
      int s = isHead ? f : (f >> 2);
      int k = s * 16 + hi * 8 + j;
      int c = (k & ~12) | ((k & 4) << 1) | ((k & 8) >> 1);   // swap bits 2,3
      if (isHead) v = (m < 2) ? src[c * 2 + m] : 0.f;
      else {
        int ch = (f & 3) * 32 + m;
        v = src[c * 128 + ch];
      }
    }
    d[idx] = f2b(v);
  }
}

// ---- main: MODE0 = r22 byte-identical (best measured: ~127us). MODE1 reads
// weight fragments straight from global/L2 (38KB L2-hot, no LDS fill, no
// barrier) with grid sized to exactly 1 batch/wave.
template <int MODE>
__global__ __launch_bounds__(512, 2)
void gnn_kernel(const float* __restrict__ nodes,
                const int* __restrict__ eidx,
                unsigned long long* __restrict__ pooled,
                const ushort* __restrict__ wsrc,
                const float* __restrict__ b1g, const float* __restrict__ b2g,
                const float* __restrict__ b3g,
                float* __restrict__ out) {
  __shared__ __align__(16) ushort wlds[(MODE == 0) ? 36864 : 8];
  __shared__ __align__(16) float bias1[(MODE == 0) ? 128 : 4];
  __shared__ __align__(16) float bias2[(MODE == 0) ? 128 : 4];
  __shared__ __align__(16) float bias3[(MODE == 0) ? 16 : 4];
  if (MODE == 0) {
    i32x4* dw = (i32x4*)wlds;
    const i32x4* sw = (const i32x4*)wsrc;
    for (int i = threadIdx.x; i < 4608; i += 512) dw[i] = sw[256 + i];  // skip W0
    if (threadIdx.x < 128) {
      bias1[threadIdx.x] = b1g[threadIdx.x];
      bias2[threadIdx.x] = b2g[threadIdx.x];
    }
    if (threadIdx.x < 16) bias3[threadIdx.x] = (threadIdx.x < 2) ? b3g[threadIdx.x] : 0.f;
  }

  const int wv = threadIdx.x >> 6;
  const int l = threadIdx.x & 63;
  const int hi = l >> 5;
  const int e32 = l & 31;
  // weight frag fetch: MODE0 from LDS (bases: W1=0, W2=16384, W3=32768 ushorts);
  // MODE1 from global (same layout at wsrc+2048, skipping W0)
  auto LF = [&](int base, int f) -> s16x8 {
    if (MODE == 0)
      return *(const s16x8*)(wlds + base + f * 512 + l * 8);
    else
      return *(const s16x8*)(wsrc + 2048 + base + f * 512 + l * 8);
  };
  // W0 persistent in registers (16 VGPRs), straight from global (L2-hot, once)
  s16x8 w0p[4];
#pragma unroll
  for (int mt = 0; mt < 4; mt++)
    w0p[mt] = *(const s16x8*)(wsrc + ((mt * 64 + l) * 8));
  if (MODE == 0) __syncthreads();
  const float* bb1 = (MODE == 0) ? (const float*)bias1 : b1g;
  const float* bb2 = (MODE == 0) ? (const float*)bias2 : b2g;
  const float b30 = (MODE == 0) ? bias3[0] : b3g[0];
  const float b31 = (MODE == 0) ? bias3[1] : b3g[1];

  int wid = blockIdx.x * 8 + wv;
  int nwv = gridDim.x * 8;
  const int NB = (MODE == 0) ? (NE / 32) : (NN / 32);
  const f32x16 z16 = {0.f, 0.f, 0.f, 0.f, 0.f, 0.f, 0.f, 0.f,
                      0.f, 0.f, 0.f, 0.f, 0.f, 0.f, 0.f, 0.f};

  // gather: lane = (edge e32, half hi). hi0 = sender/node, hi1 = receiver/pooled.
  float g0 = 0, g1 = 0, g2 = 0, g3 = 0, g4 = 0;
  auto PREF = [&](int bb) {
    if (bb < NB) {
      int e = (bb << 5) + e32;
      if (MODE == 0) {
        int idx = eidx[hi * NE + e];
        const float* np_ = nodes + idx * 5;
        g0 = np_[0]; g1 = np_[1]; g2 = np_[2]; g3 = np_[3]; g4 = np_[4];
      } else {
        if (hi == 0) {
          const float* np_ = nodes + e * 5;
          g0 = np_[0]; g1 = np_[1]; g2 = np_[2]; g3 = np_[3]; g4 = np_[4];
        } else {
          unsigned long long pl = pooled[e];
          int x32 = (int)(uint)pl;
          int y32 = (int)(pl >> 32) + (x32 < 0 ? 1 : 0);
          g0 = (float)x32 * (1.f / PSCALE);
          g1 = (float)y32 * (1.f / PSCALE);
        }
      }
    }
  };
  PREF(wid);

#pragma unroll 1
  for (int b = wid; b < NB; b += nwv) {
    const int rbase = b << 5;
    int rc = 0;
    if (MODE == 0) rc = eidx[NE + rbase + e32];
    // build the single L0 B-fragment
    s16x8 xf;
    {
      u32x4 f = {0u, 0u, 0u, 0u};
      if (MODE == 0) {
        f[0] = cvtpk(g0, g1); f[1] = cvtpk(g2, g3);
        f[2] = cvtpk(g4, hi ? 1.0f : 0.0f);          // bias rides k13 (hi=1,j=5)
      } else {
        if (hi == 0) { f[0] = cvtpk(g0, g1); f[1] = cvtpk(g2, g3); f[2] = cvtpk(g4, 0.f); }
        else         { f[0] = cvtpk(g0, g1); f[1] = cvtpk(1.0f, 0.f); }  // bias k10
      }
      xf = __builtin_bit_cast(s16x8, f);
    }
    PREF(b + nwv);

    // prefetch L1 mt=0 (8 frags) before any MFMA
    s16x8 wf[2][8];
#pragma unroll
    for (int s = 0; s < 8; s++) wf[0][s] = LF(0, s * 4);

    // L0: 4 MFMA (bias folded into W0, W0 in registers)
    u32x4 phA[4][2];
    {
      f32x16 a;
      a = mfma32(w0p[0], xf, z16); phA[0][0] = packg(a, 0); phA[0][1] = packg(a, 1);
      a = mfma32(w0p[1], xf, z16); phA[1][0] = packg(a, 0); phA[1][1] = packg(a, 1);
      a = mfma32(w0p[2], xf, z16); phA[2][0] = packg(a, 0); phA[2][1] = packg(a, 1);
      a = mfma32(w0p[3], xf, z16); phA[3][0] = packg(a, 0); phA[3][1] = packg(a, 1);
    }
    // L1: stream 32 frags, double-buffered by output tile; mt=3 preloads L2 mt=0
    u32x4 phB[4][2];
#pragma unroll
    for (int mt = 0; mt < 4; mt++) {
      if (mt < 3) {
#pragma unroll
        for (int s = 0; s < 8; s++) wf[(mt + 1) & 1][s] = LF(0, s * 4 + mt + 1);
      } else {
#pragma unroll
        for (int s = 0; s < 8; s++) wf[(mt + 1) & 1][s] = LF(16384, s * 4);
      }
      f32x16 a = loadbias(bb1, mt, hi);
#pragma unroll
      for (int s = 0; s < 8; s++)
        a = mfma32(wf[mt & 1][s], __builtin_bit_cast(s16x8, phA[s >> 1][s & 1]), a);
      phB[mt][0] = packg(a, 0);
      phB[mt][1] = packg(a, 1);
    }
    // L2: same stream; mt=3 preloads W3
    u32x4 phC[4][2];
#pragma unroll
    for (int mt = 0; mt < 4; mt++) {
      if (mt < 3) {
#pragma unroll
        for (int s = 0; s < 8; s++) wf[(mt + 1) & 1][s] = LF(16384, s * 4 + mt + 1);
      } else {
#pragma unroll
        for (int s = 0; s < 8; s++) wf[(mt + 1) & 1][s] = LF(32768, s);
      }
      f32x16 a = loadbias(bb2, mt, hi);
#pragma unroll
      for (int s = 0; s < 8; s++)
        a = mfma32(wf[mt & 1][s], __builtin_bit_cast(s16x8, phB[s >> 1][s & 1]), a);
      phC[mt][0] = packg(a, 0);
      phC[mt][1] = packg(a, 1);
    }
    // head: 8 MFMA chain; W3 frags already in wf[0]
    f32x16 a = mfma32(wf[0][0], __builtin_bit_cast(s16x8, phC[0][0]), z16);
#pragma unroll
    for (int s = 1; s < 8; s++)
      a = mfma32(wf[0][s], __builtin_bit_cast(s16x8, phC[s >> 1][s & 1]), a);

    int e = rbase + e32;
    if (hi == 0) {
      float mv0 = a[0] + b30, mv1 = a[1] + b31;
      if (MODE == 0) {
        // ONE exact fixed-point u64 atomic per edge (r14, verified)
        int ix = (int)rintf(mv0 * PSCALE);
        int iy = (int)rintf(mv1 * PSCALE);
        long long ad = (((long long)iy) << 32) + (long long)ix;
        atomicAdd(&pooled[rc], (unsigned long long)ad);
      } else {
        out[e * 5 + 2] = nodes[e * 5 + 2] + mv0;
        out[e * 5 + 3] = nodes[e * 5 + 3] + mv1;
      }
    } else if (MODE == 1) {
      out[e * 5 + 0] = nodes[e * 5 + 0];
      out[e * 5 + 1] = nodes[e * 5 + 1];
      out[e * 5 + 4] = nodes[e * 5 + 4];
    }
  }
}

extern "C" void kernel_launch(void* const* d_in, const int* in_sizes, int n_in,
                              void* d_out, int out_size, void* d_ws, size_t ws_size,
                              hipStream_t stream) {
  const float* nodes = (const float*)d_in[0];
  const int* eidx = (const int*)d_in[1];
  const float* Wm0 = (const float*)d_in[2];  const float* bm0 = (const float*)d_in[3];
  const float* Wm1 = (const float*)d_in[4];  const float* bm1 = (const float*)d_in[5];
  const float* Wm2 = (const float*)d_in[6];  const float* bm2 = (const float*)d_in[7];
  const float* Wm3 = (const float*)d_in[8];  const float* bm3 = (const float*)d_in[9];
  const float* Wu0 = (const float*)d_in[10]; const float* bu0 = (const float*)d_in[11];
  const float* Wu1 = (const float*)d_in[12]; const float* bu1 = (const float*)d_in[13];
  const float* Wu2 = (const float*)d_in[14]; const float* bu2 = (const float*)d_in[15];
  const float* Wu3 = (const float*)d_in[16]; const float* bu3 = (const float*)d_in[17];

  unsigned long long* pooled = (unsigned long long*)d_ws;  // NN u64 = 800000 B
  ushort* wbuf = (ushort*)((char*)d_ws + 800000);          // prearranged bf16 frags

  // prep (64 blocks) + pooled zeroing (16 blocks) in one dispatch
  prep_weights<<<80, 256, 0, stream>>>(Wm0, Wm1, Wm2, Wm3, Wu0, Wu1, Wu2, Wu3,
                                       bm0, bu0, wbuf, pooled);

  gnn_kernel<0><<<512, 512, 0, stream>>>(nodes, eidx, pooled, wbuf,
                                         bm1, bm2, bm3, nullptr);
  // MODE1: 3125 batches, 391 blocks x 8 waves = 1 batch/wave, weights via L2
  gnn_kernel<1><<<391, 512, 0, stream>>>(nodes, nullptr, pooled, wbuf + 38912,
                                         bu1, bu2, bu3, (float*)d_out);
}